// Round 15
// baseline (168.509 us; speedup 1.0000x reference)
//
#include <hip/hip_runtime.h>

typedef unsigned short u16;
typedef unsigned int u32;
typedef __attribute__((ext_vector_type(8))) short bf16x8;
typedef __attribute__((ext_vector_type(4))) float f32x4;

#define DEVI __device__ __forceinline__

namespace {
constexpr int LQ_ = 20, LD_ = 512, D_ = 300;
constexpr int EQ_ = 5, ED_ = 10, KC_ = 10;
constexpr int QROWS = 62, DROWS = 1543;
constexpr int QSTR = 64, DSTR = 1600;
constexpr int NCVT = 14649;
constexpr float MU_H[11] = {1.0f,0.9f,0.7f,0.5f,0.3f,0.1f,-0.1f,-0.3f,-0.5f,-0.7f,-0.9f};
}

__constant__ int P2QT_C[16] = {0,0,0,1,2,1,1,2,2,3,3,3,0,1,2,3};
__constant__ int P2DT_C[16] = {0,2,1,0,0,1,2,1,2,0,1,2,3,3,3,3};
__constant__ int NP_C[4]   = {2,2,4,4};
__constant__ int PPL_C[16] = {0,1,0,0, 2,3,0,0, 2,3,4,5, 4,5,6,7};
__constant__ int SETL_C[16]= {0,0,0,0, 0,0,0,0, 1,1,0,0, 1,1,0,0};

DEVI u16 f2bf(float f){ union{float f;u32 u;} v; v.f=f; u32 r=(v.u+0x7fffu+((v.u>>16)&1u))>>16; return (u16)r; }
DEVI float bf2f(u16 h){ union{u32 u;float f;} v; v.u=((u32)h)<<16; return v.f; }

// ---------------- prep: embcvt (0..NCVT-1) + wpack ----------------
__global__ __launch_bounds__(256) void k_prep(const float* __restrict__ emb, u16* __restrict__ emb16,
                                              const float* __restrict__ Wu, const float* __restrict__ Wb,
                                              const float* __restrict__ Wt, const float* __restrict__ Wd,
                                              u16* __restrict__ Wp){
  const int bx = blockIdx.x;
  if(bx < NCVT){
    long i4 = (long)bx*256 + threadIdx.x;
    if(i4 < 3750000){
      float4 v = ((const float4*)emb)[i4];
      ushort4 o4; o4.x=f2bf(v.x); o4.y=f2bf(v.y); o4.z=f2bf(v.z); o4.w=f2bf(v.w);
      ((ushort4*)emb16)[i4] = o4;
    }
  } else {
    const int b2 = bx - NCVT;
    const int ts = b2/10, ks = b2%10;
    const float* W; int kk, tap;
    if(ts==0){W=Wu;kk=1;tap=0;}
    else if(ts<3){W=Wb;kk=2;tap=ts-1;}
    else if(ts<6){W=Wt;kk=3;tap=ts-3;}
    else {W=Wd;kk=5;tap=ts-6;}
    for(int idx=threadIdx.x; idx<4096; idx+=256){
      int n0=idx>>9, lane=(idx>>3)&63, j=idx&7;
      int col=lane&15, kg=lane>>4;
      int d=ks*32+kg*8+j, o=n0*16+col;
      float v = (d<300)? W[((long)o*kk + tap)*300 + d] : 0.f;
      Wp[(((long)(ts*8+n0)*10+ks)*64 + lane)*8 + j] = f2bf(v);
    }
  }
}

// ---------------- main: conv doc (0..511) + conv q (512..575) + desc (576..815) ----------------
// Tap-sharing triple-acc MFMA, bow partials from LDS, then epilogues with ot ALIASING xs.
__global__ __launch_bounds__(512) void k_main(
    const int* __restrict__ dwt, const int* __restrict__ qwt,
    const int* __restrict__ qet, const int* __restrict__ det,
    const u16* __restrict__ emb16, const u16* __restrict__ Wp,
    const float* __restrict__ bu, const float* __restrict__ bb, const float* __restrict__ bt,
    const float* __restrict__ bd,
    u16* __restrict__ dcat, u16* __restrict__ qcat,
    float* __restrict__ qdm, float* __restrict__ ddm, float* __restrict__ parts)
{
  __shared__ __align__(16) char smem[52480];
  __shared__ int tokid[80];
  const int bx = blockIdx.x, t = threadIdx.x;
  const int lane=t&63, wave=t>>6, col16=lane&15, kg=lane>>4;
  if(bx < 576){
    const bool isdoc = bx < 512;
    const int seq   = isdoc? (bx>>3) : (bx-512);
    const int l0    = isdoc? (bx&7)*64 : 0;
    const int Ltok  = isdoc? LD_ : LQ_;
    u16* outp = isdoc? dcat : qcat;
    const long seqstride = isdoc? (long)DSTR*128 : (long)QSTR*128;
    u16* xs = (u16*)smem;         // 66*328*2 = 43296 B
    float* ot = (float*)smem;     // ALIASES xs (used after MFMA+bow phases)
    const int nrows = min(66, Ltok - l0);
    if(t<66) tokid[t] = (t<nrows)? (isdoc? dwt[seq*LD_+l0+t] : qwt[seq*LQ_+t]) : 0;
    __syncthreads();
    #pragma unroll
    for(int it=0; it<11; it++){
      int idx = t + it*512;
      if(idx < 66*80){
        int r=idx/80, q=idx-r*80;
        ushort4 o4;
        if(q<75 && r<nrows) o4 = *(const ushort4*)(emb16 + (long)tokid[r]*300 + q*4);
        else { o4.x=0;o4.y=0;o4.z=0;o4.w=0; }
        *(ushort4*)&xs[r*328 + q*4] = o4;
      }
    }
    __syncthreads();
    // ---- tap-sharing triple-accumulator MFMA ----
    f32x4 aU[4], aB[4], aT[4];
    #pragma unroll
    for(int mt=0;mt<4;mt++){
      aU[mt]=(f32x4){0.f,0.f,0.f,0.f};
      aB[mt]=(f32x4){0.f,0.f,0.f,0.f};
      aT[mt]=(f32x4){0.f,0.f,0.f,0.f};
    }
    #pragma unroll
    for(int h=0;h<2;h++){
      #pragma unroll
      for(int i=0;i<3;i++){
        #pragma unroll
        for(int k5=0;k5<5;k5++){
          const long wboff = ((long)h*5 + k5)*512 + lane*8;
          bf16x8 av[4];
          #pragma unroll
          for(int mt=0;mt<4;mt++)
            av[mt] = *(const bf16x8*)&xs[(mt*16+col16+i)*328 + h*160 + k5*32 + kg*8];
          {
            bf16x8 wT = *(const bf16x8*)(Wp + ((long)((3+i)*8+wave)*10)*512 + wboff);
            #pragma unroll
            for(int mt=0;mt<4;mt++)
              aT[mt]=__builtin_amdgcn_mfma_f32_16x16x32_bf16(av[mt],wT,aT[mt],0,0,0);
          }
          if(i<2){
            bf16x8 wB = *(const bf16x8*)(Wp + ((long)((1+i)*8+wave)*10)*512 + wboff);
            #pragma unroll
            for(int mt=0;mt<4;mt++)
              aB[mt]=__builtin_amdgcn_mfma_f32_16x16x32_bf16(av[mt],wB,aB[mt],0,0,0);
          }
          if(i==0){
            bf16x8 wU = *(const bf16x8*)(Wp + ((long)(wave)*10)*512 + wboff);
            #pragma unroll
            for(int mt=0;mt<4;mt++)
              aU[mt]=__builtin_amdgcn_mfma_f32_16x16x32_bf16(av[mt],wU,aU[mt],0,0,0);
          }
        }
      }
    }
    // ---- bow partials while xs still valid ----
    if(t<304){
      const int nr = isdoc? 64 : 20;
      const int g  = isdoc? (bx&7) : 0;
      float s=0.f;
      if(t<300){
        for(int r=0;r<nr;r++) s += bf2f(xs[r*328 + t]);
      }
      parts[(((long)(isdoc?64:0) + seq)*8 + g)*304 + t] = s;
    }
    __syncthreads();   // xs dead; ot takes over the same memory
    // ---- deferred epilogues: bias+relu -> ot -> l2norm -> coalesced store ----
    #pragma unroll
    for(int c=0;c<3;c++){
      const int base = (c==0)?0:((c==1)?Ltok:2*Ltok-1);
      const float* bias = (c==0)?bu:((c==1)?bb:bt);
      const float bv = bias[wave*16+col16];
      #pragma unroll
      for(int mt=0;mt<4;mt++)
        #pragma unroll
        for(int reg=0;reg<4;reg++){
          float v = (c==0? aU[mt][reg] : (c==1? aB[mt][reg] : aT[mt][reg])) + bv;
          ot[(mt*16+kg*4+reg)*132 + wave*16+col16] = fmaxf(v, 0.f);
        }
      __syncthreads();
      {
        const int p = t>>3, j = t&7;
        const int nv = min(64, (Ltok - c) - l0);
        float ss=0.f;
        if(p<nv){
          #pragma unroll
          for(int k=0;k<16;k++){ float v = ot[p*132 + j + 8*k]; ss += v*v; }
        }
        ss += __shfl_xor(ss,1); ss += __shfl_xor(ss,2); ss += __shfl_xor(ss,4);
        if(p<nv){
          float inv = 1.0f/fmaxf(sqrtf(ss),1e-10f);
          u16* ob = outp + (long)seq*seqstride + ((long)(base + l0 + p))*128 + j*16;
          #pragma unroll
          for(int hh=0;hh<2;hh++){
            bf16x8 o8;
            #pragma unroll
            for(int e=0;e<8;e++) o8[e] = (short)f2bf(ot[p*132 + j*16 + hh*8 + e]*inv);
            *(bf16x8*)(ob + hh*8) = o8;
          }
        }
      }
      __syncthreads();
    }
  } else {
    // ---- desc conv (k=5), 4 seqs per block ----
    const int d = bx - 576;
    const bool isq = d < 80;
    const int s0 = (isq? d : d-80)*4;
    const int* dt_ = isq? qet : det;
    float* dm = isq? qdm : ddm;
    u16* xs4 = (u16*)smem;   // 80*328*2 = 52480 B
    if(t<80) tokid[t] = dt_[s0*20 + t];
    __syncthreads();
    #pragma unroll
    for(int it=0; it<13; it++){
      int idx = t + it*512;
      if(idx < 80*80){
        int lr=idx/80, q=idx-lr*80;
        ushort4 o4;
        if(q<75) o4 = *(const ushort4*)(emb16 + (long)tokid[lr]*300 + q*4);
        else { o4.x=0;o4.y=0;o4.z=0;o4.w=0; }
        *(ushort4*)&xs4[lr*328 + q*4] = o4;
      }
    }
    __syncthreads();
    f32x4 acc4[4];
    #pragma unroll
    for(int s=0;s<4;s++) acc4[s]=(f32x4){0.f,0.f,0.f,0.f};
    #pragma unroll
    for(int h=0;h<2;h++){
      bf16x8 wf[25];
      #pragma unroll
      for(int tap=0;tap<5;tap++)
        #pragma unroll
        for(int k5=0;k5<5;k5++)
          wf[tap*5+k5] = *(const bf16x8*)(Wp + (((long)((6+tap)*8 + wave)*10) + h*5 + k5)*512 + lane*8);
      #pragma unroll
      for(int s=0;s<4;s++){
        #pragma unroll
        for(int tap=0;tap<5;tap++){
          const u16* xrow = &xs4[(s*20 + col16 + tap)*328 + h*160 + kg*8];
          #pragma unroll
          for(int k5=0;k5<5;k5++){
            bf16x8 a = *(const bf16x8*)(xrow + k5*32);
            acc4[s]=__builtin_amdgcn_mfma_f32_16x16x32_bf16(a,wf[tap*5+k5],acc4[s],0,0,0);
          }
        }
      }
    }
    const float bv = bd[wave*16+col16];
    #pragma unroll
    for(int s=0;s<4;s++){
      float m=-1e30f;
      #pragma unroll
      for(int reg=0;reg<4;reg++) m=fmaxf(m, acc4[s][reg]+bv);
      m=fmaxf(m,__shfl_xor(m,16));
      m=fmaxf(m,__shfl_xor(m,32));
      m=fmaxf(m,0.f);
      if(kg==0) dm[(long)(s0+s)*128 + wave*16+col16]=m;
    }
  }
}

// ---------------- entpost (+ internal bow matvec): attention + combine + l2 ----------------
__global__ __launch_bounds__(256) void k_entpost(
    const int* __restrict__ qei, const int* __restrict__ qew,
    const int* __restrict__ dei, const int* __restrict__ dew,
    const float* __restrict__ qdm, const float* __restrict__ ddm,
    const float* __restrict__ parts, const float* __restrict__ bowW, const float* __restrict__ bowb,
    const float* __restrict__ ent, const float* __restrict__ car,
    u16* __restrict__ qcat, u16* __restrict__ dcat)
{
  const int e15 = blockIdx.x, b = blockIdx.y, t = threadIdx.x;
  const bool isq = (e15 < EQ_);
  const int e = isq? e15 : e15-EQ_;
  const float* dmx = isq? (qdm + (long)(b*EQ_+e)*128) : (ddm + (long)(b*ED_+e)*128);
  const int eid = isq? qei[b*EQ_+e] : dei[b*ED_+e];
  const int* carids = isq? (qew + b*EQ_*KC_ + e*KC_) : (dew + b*ED_*KC_ + e*KC_);
  u16* orow = isq? (qcat + ((long)b*QSTR + 57 + e)*128) : (dcat + ((long)b*DSTR + 1533 + e)*128);

  __shared__ float carS[KC_*128];
  __shared__ float sv[304];
  __shared__ float bwS[128];
  __shared__ float sc[KC_], att[KC_];
  __shared__ float red[4];
  const float* p = parts + (((long)(isq?0:64) + b)*8)*304;
  const int ng = isq? 1 : 8;
  for(int d=t; d<304; d+=256){
    float s=0.f;
    for(int g=0;g<ng;g++) s += p[g*304+d];
    sv[d]=s;
  }
  for(int idx=t; idx<KC_*128; idx+=256){
    int j = idx>>7, c = idx&127;
    carS[j*128+c] = car[(long)carids[j]*128 + c];
  }
  __syncthreads();
  {
    const int ch = t>>1, h = t&1;
    float acc=0.f;
    const float* w = bowW + (long)ch*300 + h*150;
    const float* x = sv + h*150;
    for(int d=0; d<150; d++) acc += x[d]*w[d];
    acc += __shfl_xor(acc,1);
    if(h==0) bwS[ch] = acc + (isq? (float)LQ_ : (float)LD_)*bowb[ch];
  }
  __syncthreads();
  {
    const int j = t>>4, l16 = t&15;
    if(j < KC_){
      float s=0.f;
      for(int c=l16;c<128;c+=16) s += bwS[c]*carS[j*128+c];
      s += __shfl_xor(s,1); s += __shfl_xor(s,2); s += __shfl_xor(s,4); s += __shfl_xor(s,8);
      if(l16==0) sc[j]=s;
    }
  }
  __syncthreads();
  if(t==0){
    float m=-1e30f;
    for(int x=0;x<KC_;x++) m = fmaxf(m, sc[x]);
    float ssum=0.f;
    for(int x=0;x<KC_;x++){ float e2=__expf(sc[x]-m); att[x]=e2; ssum+=e2; }
    float rs = 1.0f/ssum;
    for(int x=0;x<KC_;x++) att[x]*=rs;
  }
  __syncthreads();
  float val=0.f;
  if(t<128){
    float ew=0.f;
    for(int x=0;x<KC_;x++) ew += att[x]*carS[x*128+t];
    val = ent[(long)eid*128+t] + dmx[t] + ew;
  }
  float ss = val*val;
  ss += __shfl_xor(ss,1); ss += __shfl_xor(ss,2); ss += __shfl_xor(ss,4);
  ss += __shfl_xor(ss,8); ss += __shfl_xor(ss,16); ss += __shfl_xor(ss,32);
  if((t&63)==0) red[t>>6]=ss;
  __syncthreads();
  if(t<128){
    float nv = 1.0f/fmaxf(sqrtf(red[0]+red[1]),1e-10f);
    orow[t] = f2bf(val*nv);
  }
}

// ---------------- fused sim+gauss: grid (64 b, 4 pieces), wave=(qtile,dpar) ----------------
__global__ __launch_bounds__(512) void k_simgauss(const u16* __restrict__ qcat, const u16* __restrict__ dcat,
                                                  const float* __restrict__ dwm, const float* __restrict__ dem,
                                                  float* __restrict__ Spart){
  const int b=blockIdx.x, piece=blockIdx.y;
  const int t=threadIdx.x, lane=t&63, wave=t>>6;
  const int qtile=wave>>1, dpar=wave&1;
  const int col16=lane&15, kg=lane>>4;
  constexpr int NT[4]={8,8,8,1};
  constexpr int TBASE[4]={0,8,16,24};
  constexpr int PEND[4]={512,1023,1533,1543};
  bf16x8 afr[4];
  #pragma unroll
  for(int ks=0;ks<4;ks++)
    afr[ks] = *(const bf16x8*)&qcat[((long)b*QSTR + qtile*16+col16)*128 + ks*32 + kg*8];
  float aP[4][11], aS[4][11];
  #pragma unroll
  for(int r=0;r<4;r++)
    #pragma unroll
    for(int m=0;m<11;m++){ aP[r][m]=0.f; aS[r][m]=0.f; }
  const int t0 = dpar*4;
  const int t1 = (NT[piece] < t0+4)? NT[piece] : t0+4;
  for(int tt=t0; tt<t1; tt++){
    const int tb = TBASE[piece]+tt;
    f32x4 acc[4];
    #pragma unroll
    for(int n0=0;n0<4;n0++) acc[n0]=(f32x4){0.f,0.f,0.f,0.f};
    #pragma unroll
    for(int ks=0;ks<4;ks++){
      #pragma unroll
      for(int n0=0;n0<4;n0++){
        bf16x8 bfr = *(const bf16x8*)&dcat[((long)b*DSTR + tb*64 + n0*16+col16)*128 + ks*32 + kg*8];
        acc[n0]=__builtin_amdgcn_mfma_f32_16x16x32_bf16(afr[ks],bfr,acc[n0],0,0,0);
      }
    }
    #pragma unroll
    for(int n0=0;n0<4;n0++){
      const int col = tb*64 + n0*16 + col16;
      float md;
      if(col<512) md = dwm[b*LD_+col];
      else if(col<1023) md = dwm[b*LD_+col-512];
      else if(col<1533) md = dwm[b*LD_+col-1023];
      else if(col<1543) md = dem[b*ED_+(col-1533)];
      else md = 0.f;
      const bool pr = col < PEND[piece];
      const float mdP = pr? md : 0.f;
      const float mdS = pr? 0.f : md;
      #pragma unroll
      for(int reg=0;reg<4;reg++){
        const float svv = acc[n0][reg];
        {
          float d1 = svv-1.0f;
          float e = __expf(-500000.0f*d1*d1);
          aP[reg][0] += mdP*e; aS[reg][0] += mdS*e;
        }
        #pragma unroll
        for(int m=1;m<11;m++){
          float dm = svv-MU_H[m];
          float e = __expf(-50.0f*dm*dm);
          aP[reg][m] += mdP*e; aS[reg][m] += mdS*e;
        }
      }
    }
  }
  #pragma unroll
  for(int reg=0;reg<4;reg++)
    #pragma unroll
    for(int m=0;m<11;m++){
      float vP=aP[reg][m];
      vP+=__shfl_xor(vP,1); vP+=__shfl_xor(vP,2); vP+=__shfl_xor(vP,4); vP+=__shfl_xor(vP,8);
      aP[reg][m]=vP;
      float vS=aS[reg][m];
      vS+=__shfl_xor(vS,1); vS+=__shfl_xor(vS,2); vS+=__shfl_xor(vS,4); vS+=__shfl_xor(vS,8);
      aS[reg][m]=vS;
    }
  if(col16==0){
    #pragma unroll
    for(int reg=0;reg<4;reg++){
      const int qr = qtile*16 + kg*4 + reg;
      float* o = Spart + (((long)b*64 + qr)*8 + piece*2+dpar)*22;
      #pragma unroll
      for(int m=0;m<11;m++){ o[m]=aP[reg][m]; o[11+m]=aS[reg][m]; }
    }
  }
}

// ---------------- log-pool + dense + tanh ----------------
__global__ __launch_bounds__(256) void k_feats(const float* __restrict__ Spart, const float* __restrict__ qwm,
                                               const float* __restrict__ qem, const float* __restrict__ dfW,
                                               const float* __restrict__ dfb, float* __restrict__ out){
  const int b = blockIdx.x, t = threadIdx.x;
  __shared__ float fsh[176];
  __shared__ float red[4];
  if(t<176){
    const int pool = t/11, m = t - pool*11;
    const int qt = P2QT_C[pool], dt = P2DT_C[pool];
    const int qlo = (qt==0)?0:((qt==1)?20:((qt==2)?39:57));
    const int qn  = (qt==0)?20:((qt==1)?19:((qt==2)?18:5));
    float f = 0.f;
    for(int r=0;r<qn;r++){
      const int qr = qlo + r;
      float mq = (qt<3)? qwm[b*LQ_+r] : qem[b*EQ_+r];
      const float* row = Spart + (((long)b*64 + qr)*8)*22 + m;
      float sv = 0.f;
      const int np = NP_C[dt];
      for(int k=0;k<np;k++){
        const int ii = dt*4+k;
        sv += row[PPL_C[ii]*22 + SETL_C[ii]*11];
      }
      f += logf(fmaxf(sv,1e-10f))*0.01f*mq;
    }
    fsh[t] = f;
  }
  __syncthreads();
  float v = (t<176)? fsh[t]*dfW[t] : 0.f;
  v += __shfl_xor(v,1); v += __shfl_xor(v,2); v += __shfl_xor(v,4);
  v += __shfl_xor(v,8); v += __shfl_xor(v,16); v += __shfl_xor(v,32);
  if((t&63)==0) red[t>>6]=v;
  __syncthreads();
  if(t==0) out[b] = tanhf(red[0]+red[1]+red[2]+red[3] + dfb[0]);
}

extern "C" void kernel_launch(void* const* d_in, const int* in_sizes, int n_in,
                              void* d_out, int out_size, void* d_ws, size_t ws_size,
                              hipStream_t stream)
{
  const int*   qwt=(const int*)d_in[0];
  const float* qwm=(const float*)d_in[1];
  const int*   qei=(const int*)d_in[2];
  const int*   qet=(const int*)d_in[3];
  const int*   qew=(const int*)d_in[4];
  const float* qem=(const float*)d_in[5];
  const int*   dwt=(const int*)d_in[6];
  const float* dwm=(const float*)d_in[7];
  const int*   dei=(const int*)d_in[8];
  const int*   det=(const int*)d_in[9];
  const int*   dew=(const int*)d_in[10];
  const float* dem=(const float*)d_in[11];
  const float* emb=(const float*)d_in[12];
  const float* ent=(const float*)d_in[13];
  const float* car=(const float*)d_in[14];
  const float* bowW=(const float*)d_in[15];
  const float* bowb=(const float*)d_in[16];
  const float* Wu=(const float*)d_in[17];
  const float* bu=(const float*)d_in[18];
  const float* Wb=(const float*)d_in[19];
  const float* bb=(const float*)d_in[20];
  const float* Wt=(const float*)d_in[21];
  const float* bt=(const float*)d_in[22];
  const float* Wd=(const float*)d_in[23];
  const float* bd=(const float*)d_in[24];
  const float* dfW=(const float*)d_in[25];
  const float* dfb=(const float*)d_in[26];
  float* out=(float*)d_out;

  char* ws=(char*)d_ws;
  size_t off=0;
  auto A=[&](size_t n){ size_t r=off; off=(off+n+255)&~(size_t)255; return r; };
  u16* Wp     = (u16*)(ws + A((size_t)11*8*10*64*8*2));
  u16* dcat   = (u16*)(ws + A((size_t)64*DSTR*128*2));
  u16* qcat   = (u16*)(ws + A((size_t)64*QSTR*128*2));
  float* qdm  = (float*)(ws + A((size_t)320*128*4));
  float* ddm  = (float*)(ws + A((size_t)640*128*4));
  float* parts= (float*)(ws + A((size_t)2*64*8*304*4));
  float* Spart= (float*)(ws + A((size_t)64*64*8*22*4));
  u16* emb16  = (u16*)(ws + A((size_t)50000*300*2));
  if(off > ws_size) return;

  k_prep<<<NCVT+110,256,0,stream>>>(emb,emb16,Wu,Wb,Wt,Wd,Wp);
  k_main<<<816,512,0,stream>>>(dwt,qwt,qet,det,emb16,Wp,bu,bb,bt,bd,dcat,qcat,qdm,ddm,parts);
  k_entpost<<<dim3(15,64),256,0,stream>>>(qei,qew,dei,dew,qdm,ddm,parts,bowW,bowb,ent,car,qcat,dcat);
  k_simgauss<<<dim3(64,4),512,0,stream>>>(qcat,dcat,dwm,dem,Spart);
  k_feats<<<64,256,0,stream>>>(Spart,qwm,qem,dfW,dfb,out);
}

// Round 16
// 154.778 us; speedup vs baseline: 1.0887x; 1.0887x over previous
//
#include <hip/hip_runtime.h>

typedef unsigned short u16;
typedef unsigned int u32;
typedef __attribute__((ext_vector_type(8))) short bf16x8;
typedef __attribute__((ext_vector_type(4))) float f32x4;

#define DEVI __device__ __forceinline__

namespace {
constexpr int LQ_ = 20, LD_ = 512, D_ = 300;
constexpr int EQ_ = 5, ED_ = 10, KC_ = 10;
constexpr int QROWS = 62, DROWS = 1543;
constexpr int QSTR = 64, DSTR = 1600;
constexpr int NCVT = 14649;         // 15e6 elems / 4 per thread / 256
constexpr float MU_H[11] = {1.0f,0.9f,0.7f,0.5f,0.3f,0.1f,-0.1f,-0.3f,-0.5f,-0.7f,-0.9f};
}

__constant__ int P2QT_C[16] = {0,0,0,1,2,1,1,2,2,3,3,3,0,1,2,3};
__constant__ int P2DT_C[16] = {0,2,1,0,0,1,2,1,2,0,1,2,3,3,3,3};
__constant__ int NP_C[4]   = {2,2,4,4};
__constant__ int PPL_C[16] = {0,1,0,0, 2,3,0,0, 2,3,4,5, 4,5,6,7};
__constant__ int SETL_C[16]= {0,0,0,0, 0,0,0,0, 1,1,0,0, 1,1,0,0};

DEVI u16 f2bf(float f){ union{float f;u32 u;} v; v.f=f; u32 r=(v.u+0x7fffu+((v.u>>16)&1u))>>16; return (u16)r; }
DEVI float bf2f(u16 h){ union{u32 u;float f;} v; v.u=((u32)h)<<16; return v.f; }

// ---------------- prep: embcvt (0..NCVT-1) + wpack (NCVT..NCVT+109) ----------------
__global__ __launch_bounds__(256) void k_prep(const float* __restrict__ emb, u16* __restrict__ emb16,
                                              const float* __restrict__ Wu, const float* __restrict__ Wb,
                                              const float* __restrict__ Wt, const float* __restrict__ Wd,
                                              u16* __restrict__ Wp){
  const int bx = blockIdx.x;
  if(bx < NCVT){
    long i4 = (long)bx*256 + threadIdx.x;
    if(i4 < 3750000){
      float4 v = ((const float4*)emb)[i4];
      ushort4 o4; o4.x=f2bf(v.x); o4.y=f2bf(v.y); o4.z=f2bf(v.z); o4.w=f2bf(v.w);
      ((ushort4*)emb16)[i4] = o4;
    }
  } else {
    const int b2 = bx - NCVT;
    const int ts = b2/10, ks = b2%10;
    const float* W; int kk, tap;
    if(ts==0){W=Wu;kk=1;tap=0;}
    else if(ts<3){W=Wb;kk=2;tap=ts-1;}
    else if(ts<6){W=Wt;kk=3;tap=ts-3;}
    else {W=Wd;kk=5;tap=ts-6;}
    for(int idx=threadIdx.x; idx<4096; idx+=256){
      int n0=idx>>9, lane=(idx>>3)&63, j=idx&7;
      int col=lane&15, kg=lane>>4;
      int d=ks*32+kg*8+j, o=n0*16+col;
      float v = (d<300)? W[((long)o*kk + tap)*300 + d] : 0.f;
      Wp[(((long)(ts*8+n0)*10+ks)*64 + lane)*8 + j] = f2bf(v);
    }
  }
}

// ---------------- main: conv doc (0..511) + conv q (512..575) + desc (576..815) ----------------
// Staging from bf16 emb16 (row stride 300, packed). Bow partials fused from LDS after conv.
__global__ __launch_bounds__(512) void k_main(
    const int* __restrict__ dwt, const int* __restrict__ qwt,
    const int* __restrict__ qet, const int* __restrict__ det,
    const u16* __restrict__ emb16, const u16* __restrict__ Wp,
    const float* __restrict__ bu, const float* __restrict__ bb, const float* __restrict__ bt,
    const float* __restrict__ bd,
    u16* __restrict__ dcat, u16* __restrict__ qcat,
    float* __restrict__ qdm, float* __restrict__ ddm, float* __restrict__ parts)
{
  __shared__ __align__(16) char smem[77088];
  __shared__ int tokid[80];
  const int bx = blockIdx.x, t = threadIdx.x;
  const int lane=t&63, wave=t>>6, col16=lane&15, kg=lane>>4;
  if(bx < 576){
    // ---- uni/bi/tri conv, 64-row tile ----
    const bool isdoc = bx < 512;
    const int seq   = isdoc? (bx>>3) : (bx-512);
    const int l0    = isdoc? (bx&7)*64 : 0;
    const int Ltok  = isdoc? LD_ : LQ_;
    u16* outp = isdoc? dcat : qcat;
    const long seqstride = isdoc? (long)DSTR*128 : (long)QSTR*128;
    u16* xs = (u16*)smem;               // 66*328*2 = 43296 B
    float* ot = (float*)(smem + 43296); // 64*132*4 = 33792 B
    const int nrows = min(66, Ltok - l0);
    if(t<66) tokid[t] = (t<nrows)? (isdoc? dwt[seq*LD_+l0+t] : qwt[seq*LQ_+t]) : 0;
    __syncthreads();
    #pragma unroll
    for(int it=0; it<11; it++){
      int idx = t + it*512;
      if(idx < 66*80){
        int r=idx/80, q=idx-r*80;
        ushort4 o4;
        if(q<75 && r<nrows) o4 = *(const ushort4*)(emb16 + (long)tokid[r]*300 + q*4);
        else { o4.x=0;o4.y=0;o4.z=0;o4.w=0; }
        *(ushort4*)&xs[r*328 + q*4] = o4;
      }
    }
    __syncthreads();
    #pragma unroll
    for(int c=0;c<3;c++){
      const int tb = (c==0)?0:((c==1)?1:3);
      const int base = (c==0)?0:((c==1)?Ltok:2*Ltok-1);
      const float* bias = (c==0)?bu:((c==1)?bb:bt);
      f32x4 acc4[4];
      #pragma unroll
      for(int mt=0;mt<4;mt++) acc4[mt]=(f32x4){0.f,0.f,0.f,0.f};
      #pragma unroll
      for(int h=0;h<2;h++){
        bf16x8 wf[15];
        #pragma unroll
        for(int i=0;i<=c;i++)
          #pragma unroll
          for(int k5=0;k5<5;k5++)
            wf[i*5+k5] = *(const bf16x8*)(Wp + (((long)((tb+i)*8 + wave)*10) + h*5 + k5)*512 + lane*8);
        #pragma unroll
        for(int mt=0;mt<4;mt++){
          #pragma unroll
          for(int i=0;i<=c;i++){
            const u16* xrow = &xs[(mt*16 + col16 + i)*328 + h*160 + kg*8];
            #pragma unroll
            for(int k5=0;k5<5;k5++){
              bf16x8 a = *(const bf16x8*)(xrow + k5*32);
              acc4[mt]=__builtin_amdgcn_mfma_f32_16x16x32_bf16(a,wf[i*5+k5],acc4[mt],0,0,0);
            }
          }
        }
      }
      const float bv = bias[wave*16+col16];
      #pragma unroll
      for(int mt=0;mt<4;mt++)
        #pragma unroll
        for(int reg=0;reg<4;reg++)
          ot[(mt*16+kg*4+reg)*132 + wave*16+col16] = fmaxf(acc4[mt][reg]+bv, 0.f);
      __syncthreads();
      {
        const int p = t>>3, j = t&7;
        const int nv = min(64, (Ltok - c) - l0);
        float ss=0.f;
        if(p<nv){
          #pragma unroll
          for(int k=0;k<16;k++){ float v = ot[p*132 + j + 8*k]; ss += v*v; }
        }
        ss += __shfl_xor(ss,1); ss += __shfl_xor(ss,2); ss += __shfl_xor(ss,4);
        if(p<nv){
          float inv = 1.0f/fmaxf(sqrtf(ss),1e-10f);
          u16* ob = outp + (long)seq*seqstride + ((long)(base + l0 + p))*128 + j*16;
          #pragma unroll
          for(int hh=0;hh<2;hh++){
            bf16x8 o8;
            #pragma unroll
            for(int e=0;e<8;e++) o8[e] = (short)f2bf(ot[p*132 + j*16 + hh*8 + e]*inv);
            *(bf16x8*)(ob + hh*8) = o8;
          }
        }
      }
      __syncthreads();
    }
    // ---- fused bow partials from LDS tile (xs intact) ----
    {
      const int nr = isdoc? 64 : 20;
      const int g  = isdoc? (bx&7) : 0;
      const int b  = seq;
      if(t<304){
        float s=0.f;
        if(t<300){
          for(int r=0;r<nr;r++) s += bf2f(xs[r*328 + t]);
        }
        parts[(((long)(isdoc?64:0) + b)*8 + g)*304 + t] = s;
      }
    }
  } else {
    // ---- desc conv (k=5), 4 seqs per block ----
    const int d = bx - 576;
    const bool isq = d < 80;
    const int s0 = (isq? d : d-80)*4;
    const int* dt_ = isq? qet : det;
    float* dm = isq? qdm : ddm;
    u16* xs4 = (u16*)smem;   // 80*328*2 = 52480 B
    if(t<80) tokid[t] = dt_[s0*20 + t];
    __syncthreads();
    #pragma unroll
    for(int it=0; it<13; it++){
      int idx = t + it*512;
      if(idx < 80*80){
        int lr=idx/80, q=idx-lr*80;
        ushort4 o4;
        if(q<75) o4 = *(const ushort4*)(emb16 + (long)tokid[lr]*300 + q*4);
        else { o4.x=0;o4.y=0;o4.z=0;o4.w=0; }
        *(ushort4*)&xs4[lr*328 + q*4] = o4;
      }
    }
    __syncthreads();
    f32x4 acc4[4];
    #pragma unroll
    for(int s=0;s<4;s++) acc4[s]=(f32x4){0.f,0.f,0.f,0.f};
    #pragma unroll
    for(int h=0;h<2;h++){
      bf16x8 wf[25];
      #pragma unroll
      for(int tap=0;tap<5;tap++)
        #pragma unroll
        for(int k5=0;k5<5;k5++)
          wf[tap*5+k5] = *(const bf16x8*)(Wp + (((long)((6+tap)*8 + wave)*10) + h*5 + k5)*512 + lane*8);
      #pragma unroll
      for(int s=0;s<4;s++){
        #pragma unroll
        for(int tap=0;tap<5;tap++){
          const u16* xrow = &xs4[(s*20 + col16 + tap)*328 + h*160 + kg*8];
          #pragma unroll
          for(int k5=0;k5<5;k5++){
            bf16x8 a = *(const bf16x8*)(xrow + k5*32);
            acc4[s]=__builtin_amdgcn_mfma_f32_16x16x32_bf16(a,wf[tap*5+k5],acc4[s],0,0,0);
          }
        }
      }
    }
    const float bv = bd[wave*16+col16];
    #pragma unroll
    for(int s=0;s<4;s++){
      float m=-1e30f;
      #pragma unroll
      for(int reg=0;reg<4;reg++) m=fmaxf(m, acc4[s][reg]+bv);
      m=fmaxf(m,__shfl_xor(m,16));
      m=fmaxf(m,__shfl_xor(m,32));
      m=fmaxf(m,0.f);
      if(kg==0) dm[(long)(s0+s)*128 + wave*16+col16]=m;
    }
  }
}

// ---------------- bow matvec (dedup): 128 blocks = (side,b), 128 threads ----------------
__global__ __launch_bounds__(128) void k_bowmat(const float* __restrict__ parts,
                                                const float* __restrict__ bowW, const float* __restrict__ bowb,
                                                float* __restrict__ qbow, float* __restrict__ dbow){
  const int side = blockIdx.x>>6, b = blockIdx.x&63, t = threadIdx.x;
  __shared__ float sv[304];
  const float* p = parts + (((long)side*64 + b)*8)*304;
  const int ng = side? 8 : 1;
  for(int d=t; d<304; d+=128){
    float s=0.f;
    for(int g=0;g<ng;g++) s += p[g*304+d];
    sv[d]=s;
  }
  __syncthreads();
  float acc=0.f;
  const float* w = bowW + (long)t*D_;
  for(int d=0; d<D_; d++) acc += sv[d]*w[d];
  const float L = side? (float)LD_ : (float)LQ_;
  (side? dbow:qbow)[b*128+t] = acc + L*bowb[t];
}

// ---------------- entpost: attention + combine + l2 ----------------
__global__ __launch_bounds__(256) void k_entpost(
    const int* __restrict__ qei, const int* __restrict__ qew,
    const int* __restrict__ dei, const int* __restrict__ dew,
    const float* __restrict__ qdm, const float* __restrict__ ddm,
    const float* __restrict__ qbow, const float* __restrict__ dbow,
    const float* __restrict__ ent, const float* __restrict__ car,
    u16* __restrict__ qcat, u16* __restrict__ dcat)
{
  const int e15 = blockIdx.x, b = blockIdx.y, t = threadIdx.x;
  const bool isq = (e15 < EQ_);
  const int e = isq? e15 : e15-EQ_;
  const float* dmx = isq? (qdm + (long)(b*EQ_+e)*128) : (ddm + (long)(b*ED_+e)*128);
  const float* bw = isq? (qbow + b*128) : (dbow + b*128);
  const int eid = isq? qei[b*EQ_+e] : dei[b*ED_+e];
  const int* carids = isq? (qew + b*EQ_*KC_ + e*KC_) : (dew + b*ED_*KC_ + e*KC_);
  u16* orow = isq? (qcat + ((long)b*QSTR + 57 + e)*128) : (dcat + ((long)b*DSTR + 1533 + e)*128);

  __shared__ float carS[KC_*128];
  __shared__ float sc[KC_], att[KC_];
  __shared__ float red[4];
  for(int idx=t; idx<KC_*128; idx+=256){
    int j = idx>>7, c = idx&127;
    carS[j*128+c] = car[(long)carids[j]*128 + c];
  }
  __syncthreads();
  {
    const int j = t>>4, l16 = t&15;
    if(j < KC_){
      float s=0.f;
      for(int c=l16;c<128;c+=16) s += bw[c]*carS[j*128+c];
      s += __shfl_xor(s,1); s += __shfl_xor(s,2); s += __shfl_xor(s,4); s += __shfl_xor(s,8);
      if(l16==0) sc[j]=s;
    }
  }
  __syncthreads();
  if(t==0){
    float m=-1e30f;
    for(int x=0;x<KC_;x++) m = fmaxf(m, sc[x]);
    float ssum=0.f;
    for(int x=0;x<KC_;x++){ float e2=__expf(sc[x]-m); att[x]=e2; ssum+=e2; }
    float rs = 1.0f/ssum;
    for(int x=0;x<KC_;x++) att[x]*=rs;
  }
  __syncthreads();
  float val=0.f;
  if(t<128){
    float ew=0.f;
    for(int x=0;x<KC_;x++) ew += att[x]*carS[x*128+t];
    val = ent[(long)eid*128+t] + dmx[t] + ew;
  }
  float ss = val*val;
  ss += __shfl_xor(ss,1); ss += __shfl_xor(ss,2); ss += __shfl_xor(ss,4);
  ss += __shfl_xor(ss,8); ss += __shfl_xor(ss,16); ss += __shfl_xor(ss,32);
  if((t&63)==0) red[t>>6]=ss;
  __syncthreads();
  if(t<128){
    float nv = 1.0f/fmaxf(sqrtf(red[0]+red[1]),1e-10f);
    orow[t] = f2bf(val*nv);
  }
}

// ---------------- fused sim+gauss: grid (64 b, 4 pieces), wave=(qtile,dpar) ----------------
__global__ __launch_bounds__(512) void k_simgauss(const u16* __restrict__ qcat, const u16* __restrict__ dcat,
                                                  const float* __restrict__ dwm, const float* __restrict__ dem,
                                                  float* __restrict__ Spart){
  const int b=blockIdx.x, piece=blockIdx.y;
  const int t=threadIdx.x, lane=t&63, wave=t>>6;
  const int qtile=wave>>1, dpar=wave&1;
  const int col16=lane&15, kg=lane>>4;
  constexpr int NT[4]={8,8,8,1};
  constexpr int TBASE[4]={0,8,16,24};
  constexpr int PEND[4]={512,1023,1533,1543};
  bf16x8 afr[4];
  #pragma unroll
  for(int ks=0;ks<4;ks++)
    afr[ks] = *(const bf16x8*)&qcat[((long)b*QSTR + qtile*16+col16)*128 + ks*32 + kg*8];
  float aP[4][11], aS[4][11];
  #pragma unroll
  for(int r=0;r<4;r++)
    #pragma unroll
    for(int m=0;m<11;m++){ aP[r][m]=0.f; aS[r][m]=0.f; }
  const int t0 = dpar*4;
  const int t1 = (NT[piece] < t0+4)? NT[piece] : t0+4;
  for(int tt=t0; tt<t1; tt++){
    const int tb = TBASE[piece]+tt;
    f32x4 acc[4];
    #pragma unroll
    for(int n0=0;n0<4;n0++) acc[n0]=(f32x4){0.f,0.f,0.f,0.f};
    #pragma unroll
    for(int ks=0;ks<4;ks++){
      #pragma unroll
      for(int n0=0;n0<4;n0++){
        bf16x8 bfr = *(const bf16x8*)&dcat[((long)b*DSTR + tb*64 + n0*16+col16)*128 + ks*32 + kg*8];
        acc[n0]=__builtin_amdgcn_mfma_f32_16x16x32_bf16(afr[ks],bfr,acc[n0],0,0,0);
      }
    }
    #pragma unroll
    for(int n0=0;n0<4;n0++){
      const int col = tb*64 + n0*16 + col16;
      float md;
      if(col<512) md = dwm[b*LD_+col];
      else if(col<1023) md = dwm[b*LD_+col-512];
      else if(col<1533) md = dwm[b*LD_+col-1023];
      else if(col<1543) md = dem[b*ED_+(col-1533)];
      else md = 0.f;
      const bool pr = col < PEND[piece];
      const float mdP = pr? md : 0.f;
      const float mdS = pr? 0.f : md;
      #pragma unroll
      for(int reg=0;reg<4;reg++){
        const float svv = acc[n0][reg];
        {
          float d1 = svv-1.0f;
          float e = __expf(-500000.0f*d1*d1);
          aP[reg][0] += mdP*e; aS[reg][0] += mdS*e;
        }
        #pragma unroll
        for(int m=1;m<11;m++){
          float dm = svv-MU_H[m];
          float e = __expf(-50.0f*dm*dm);
          aP[reg][m] += mdP*e; aS[reg][m] += mdS*e;
        }
      }
    }
  }
  #pragma unroll
  for(int reg=0;reg<4;reg++)
    #pragma unroll
    for(int m=0;m<11;m++){
      float vP=aP[reg][m];
      vP+=__shfl_xor(vP,1); vP+=__shfl_xor(vP,2); vP+=__shfl_xor(vP,4); vP+=__shfl_xor(vP,8);
      aP[reg][m]=vP;
      float vS=aS[reg][m];
      vS+=__shfl_xor(vS,1); vS+=__shfl_xor(vS,2); vS+=__shfl_xor(vS,4); vS+=__shfl_xor(vS,8);
      aS[reg][m]=vS;
    }
  if(col16==0){
    #pragma unroll
    for(int reg=0;reg<4;reg++){
      const int qr = qtile*16 + kg*4 + reg;
      float* o = Spart + (((long)b*64 + qr)*8 + piece*2+dpar)*22;
      #pragma unroll
      for(int m=0;m<11;m++){ o[m]=aP[reg][m]; o[11+m]=aS[reg][m]; }
    }
  }
}

// ---------------- log-pool + dense + tanh ----------------
__global__ __launch_bounds__(256) void k_feats(const float* __restrict__ Spart, const float* __restrict__ qwm,
                                               const float* __restrict__ qem, const float* __restrict__ dfW,
                                               const float* __restrict__ dfb, float* __restrict__ out){
  const int b = blockIdx.x, t = threadIdx.x;
  __shared__ float fsh[176];
  __shared__ float red[4];
  if(t<176){
    const int pool = t/11, m = t - pool*11;
    const int qt = P2QT_C[pool], dt = P2DT_C[pool];
    const int qlo = (qt==0)?0:((qt==1)?20:((qt==2)?39:57));
    const int qn  = (qt==0)?20:((qt==1)?19:((qt==2)?18:5));
    float f = 0.f;
    for(int r=0;r<qn;r++){
      const int qr = qlo + r;
      float mq = (qt<3)? qwm[b*LQ_+r] : qem[b*EQ_+r];
      const float* row = Spart + (((long)b*64 + qr)*8)*22 + m;
      float sv = 0.f;
      const int np = NP_C[dt];
      for(int k=0;k<np;k++){
        const int ii = dt*4+k;
        sv += row[PPL_C[ii]*22 + SETL_C[ii]*11];
      }
      f += logf(fmaxf(sv,1e-10f))*0.01f*mq;
    }
    fsh[t] = f;
  }
  __syncthreads();
  float v = (t<176)? fsh[t]*dfW[t] : 0.f;
  v += __shfl_xor(v,1); v += __shfl_xor(v,2); v += __shfl_xor(v,4);
  v += __shfl_xor(v,8); v += __shfl_xor(v,16); v += __shfl_xor(v,32);
  if((t&63)==0) red[t>>6]=v;
  __syncthreads();
  if(t==0) out[b] = tanhf(red[0]+red[1]+red[2]+red[3] + dfb[0]);
}

extern "C" void kernel_launch(void* const* d_in, const int* in_sizes, int n_in,
                              void* d_out, int out_size, void* d_ws, size_t ws_size,
                              hipStream_t stream)
{
  const int*   qwt=(const int*)d_in[0];
  const float* qwm=(const float*)d_in[1];
  const int*   qei=(const int*)d_in[2];
  const int*   qet=(const int*)d_in[3];
  const int*   qew=(const int*)d_in[4];
  const float* qem=(const float*)d_in[5];
  const int*   dwt=(const int*)d_in[6];
  const float* dwm=(const float*)d_in[7];
  const int*   dei=(const int*)d_in[8];
  const int*   det=(const int*)d_in[9];
  const int*   dew=(const int*)d_in[10];
  const float* dem=(const float*)d_in[11];
  const float* emb=(const float*)d_in[12];
  const float* ent=(const float*)d_in[13];
  const float* car=(const float*)d_in[14];
  const float* bowW=(const float*)d_in[15];
  const float* bowb=(const float*)d_in[16];
  const float* Wu=(const float*)d_in[17];
  const float* bu=(const float*)d_in[18];
  const float* Wb=(const float*)d_in[19];
  const float* bb=(const float*)d_in[20];
  const float* Wt=(const float*)d_in[21];
  const float* bt=(const float*)d_in[22];
  const float* Wd=(const float*)d_in[23];
  const float* bd=(const float*)d_in[24];
  const float* dfW=(const float*)d_in[25];
  const float* dfb=(const float*)d_in[26];
  float* out=(float*)d_out;

  char* ws=(char*)d_ws;
  size_t off=0;
  auto A=[&](size_t n){ size_t r=off; off=(off+n+255)&~(size_t)255; return r; };
  u16* Wp     = (u16*)(ws + A((size_t)11*8*10*64*8*2));
  u16* dcat   = (u16*)(ws + A((size_t)64*DSTR*128*2));
  u16* qcat   = (u16*)(ws + A((size_t)64*QSTR*128*2));
  float* qdm  = (float*)(ws + A((size_t)320*128*4));
  float* ddm  = (float*)(ws + A((size_t)640*128*4));
  float* parts= (float*)(ws + A((size_t)2*64*8*304*4));
  float* qbow = (float*)(ws + A((size_t)64*128*4));
  float* dbow = (float*)(ws + A((size_t)64*128*4));
  float* Spart= (float*)(ws + A((size_t)64*64*8*22*4));
  u16* emb16  = (u16*)(ws + A((size_t)50000*300*2));
  if(off > ws_size) return;

  k_prep<<<NCVT+110,256,0,stream>>>(emb,emb16,Wu,Wb,Wt,Wd,Wp);
  k_main<<<816,512,0,stream>>>(dwt,qwt,qet,det,emb16,Wp,bu,bb,bt,bd,dcat,qcat,qdm,ddm,parts);
  k_bowmat<<<128,128,0,stream>>>(parts,bowW,bowb,qbow,dbow);
  k_entpost<<<dim3(15,64),256,0,stream>>>(qei,qew,dei,dew,qdm,ddm,qbow,dbow,ent,car,qcat,dcat);
  k_simgauss<<<dim3(64,4),512,0,stream>>>(qcat,dcat,dwm,dem,Spart);
  k_feats<<<64,256,0,stream>>>(Spart,qwm,qem,dfW,dfb,out);
}